// Round 10
// baseline (77.674 us; speedup 1.0000x reference)
//
#include <hip/hip_runtime.h>
#include <hip/hip_bf16.h>

#define B_SZ 4096
#define F_N  39
#define V_N  100000
#define D_N  16
#define H_N  400
#define K1   624      // F*D
#define K1P  640      // K1 padded to mult of 64
#define NP   512      // H padded to mult of 64

typedef __attribute__((ext_vector_type(8))) short short8;
typedef __attribute__((ext_vector_type(4))) float f32x4;

typedef const __attribute__((address_space(1))) void g_void;
typedef __attribute__((address_space(3))) void l_void;

#define GB       1024                 // gather blocks, 4 rows each
#define W1_TILES (10 * 8)             // K1P/64 x NP/64
#define W2_TILES (8 * 8)              // 8 x 8
#define PREP_GRID (GB + W1_TILES + W2_TILES + 1)

// DIAGNOSTIC (this round only): amplify random-load traffic 8x.
// 7 dummy reps use index-perturbed addresses (distinct DRAM lines, same
// distribution), results kept live via asm volatile (rule #17), no effect
// on outputs. dur_us ≈ base + 7 * g  =>  g = true random-gather cost.
#define DUMMY_REP 7

// ---- kernel 1: high-MLP gather + fst + FM, fused with weight prep ----------
__global__ __launch_bounds__(256) void prep_kernel(
    const int*   __restrict__ Xi,
    const float* __restrict__ Xv,
    const float* __restrict__ fst_t,
    const float* __restrict__ sec_t,
    const float* __restrict__ bias,
    const float* __restrict__ W1, const float* __restrict__ b1,
    const float* __restrict__ W2, const float* __restrict__ b2,
    __hip_bfloat16* __restrict__ sec_flat,
    __hip_bfloat16* __restrict__ W1t, __hip_bfloat16* __restrict__ W2t,
    float* __restrict__ b1p, float* __restrict__ b2p,
    float* __restrict__ out)
{
    const int bid = blockIdx.x;
    const int tid = threadIdx.x;

    __shared__ float smem[4 * K1];     // 4 rows of sec values (fp32)
    __shared__ int   sidx4[4 * F_N];
    __shared__ float sval4[4 * F_N];
    __shared__ float ttile[64 * 65];   // transpose staging

    if (bid < GB) {
        // ---------------- gather branch: 4 rows, 1 wave per row -------------
        const int r = tid >> 6;        // row 0..3  (= wave id)
        const int l = tid & 63;

        if (tid < 4 * F_N) {           // 156 coalesced idx/val loads
            sidx4[tid] = Xi[bid * (4 * F_N) + tid];
            sval4[tid] = Xv[bid * (4 * F_N) + tid];
        }
        __syncthreads();

        // ---- DIAGNOSTIC dummy reps: same access pattern, shifted indices ---
        for (int rep = 1; rep <= DUMMY_REP; ++rep) {
            const int off = rep * 12347;            // < V_N, so one cond-sub mods
            #pragma unroll
            for (int it = 0; it < 4; ++it) {
                const int t = l + it * 64;
                if (t < 156) {
                    const int f = t >> 2, q = t & 3;
                    int idx = sidx4[r * F_N + f] + off;
                    if (idx >= V_N) idx -= V_N;
                    float4 dv = *(const float4*)(sec_t +
                                 ((long long)f * V_N + idx) * D_N + q * 4);
                    asm volatile("" :: "v"(dv.x), "v"(dv.y), "v"(dv.z), "v"(dv.w));
                }
                if (t >= 156 && t < 156 + F_N) {
                    const int ff = t - 156;
                    int idx = sidx4[r * F_N + ff] + off;
                    if (idx >= V_N) idx -= V_N;
                    float dfv = fst_t[(long long)ff * V_N + idx];
                    asm volatile("" :: "v"(dfv));
                }
            }
        }

        // ---- real gather (identical to round 9) ----------------------------
        float4 gv[4];
        float  fv[4];
        #pragma unroll
        for (int it = 0; it < 4; ++it) {
            const int t = l + it * 64;             // 0..255
            gv[it] = make_float4(0.f, 0.f, 0.f, 0.f);
            fv[it] = 0.f;
            if (t < 156) {
                const int f = t >> 2, q = t & 3;
                gv[it] = *(const float4*)(sec_t +
                         ((long long)f * V_N + sidx4[r * F_N + f]) * D_N + q * 4);
            }
            if (t >= 156 && t < 156 + F_N) {
                const int ff = t - 156;
                fv[it] = fst_t[(long long)ff * V_N + sidx4[r * F_N + ff]];
            }
        }

        float ssq = 0.f, fstp = 0.f;
        #pragma unroll
        for (int it = 0; it < 4; ++it) {
            const int t = l + it * 64;
            if (t < 160) {
                float4 v = make_float4(0.f, 0.f, 0.f, 0.f);
                if (t < 156) {
                    const float val = sval4[r * F_N + (t >> 2)];
                    v.x = gv[it].x * val; v.y = gv[it].y * val;
                    v.z = gv[it].z * val; v.w = gv[it].w * val;
                    *(float4*)(smem + r * K1 + t * 4) = v;
                    ssq += v.x * v.x + v.y * v.y + v.z * v.z + v.w * v.w;
                }
                ushort4 pk;
                pk.x = __bfloat16_as_ushort(__float2bfloat16(v.x));
                pk.y = __bfloat16_as_ushort(__float2bfloat16(v.y));
                pk.z = __bfloat16_as_ushort(__float2bfloat16(v.z));
                pk.w = __bfloat16_as_ushort(__float2bfloat16(v.w));
                *(ushort4*)(sec_flat + (size_t)(bid * 4 + r) * K1P + t * 4) = pk;
            }
            if (t >= 156 && t < 156 + F_N)
                fstp += fv[it] * sval4[r * F_N + (t - 156)];
        }

        float part = fstp - 0.5f * ssq;
        if (l < D_N) {
            float sd = 0.f;
            #pragma unroll
            for (int f = 0; f < F_N; ++f)
                sd += smem[r * K1 + f * D_N + l];
            part += 0.5f * sd * sd;
        }
        #pragma unroll
        for (int off = 1; off < 64; off <<= 1)
            part += __shfl_xor(part, off, 64);
        if (l == 0) out[bid * 4 + r] = part + bias[0];
        return;
    }

    int tb = bid - GB;
    if (tb < W1_TILES + W2_TILES) {
        // ---------------- weight transpose branch ---------------------------
        const float* Wsrc; __hip_bfloat16* Wdst;
        int Ksrc, Kdst, kb, nb2;
        if (tb < W1_TILES) { Wsrc = W1; Wdst = W1t; Ksrc = K1;  Kdst = K1P; kb = tb >> 3; nb2 = tb & 7; }
        else { tb -= W1_TILES; Wsrc = W2; Wdst = W2t; Ksrc = H_N; Kdst = NP; kb = tb >> 3; nb2 = tb & 7; }
        const int k0 = kb * 64, n0 = nb2 * 64;
        #pragma unroll
        for (int p = 0; p < 4; ++p) {
            const int r  = (tid >> 4) + p * 16;   // src row (k)
            const int c4 = (tid & 15) * 4;        // src col (n)
            const int gk = k0 + r, gn = n0 + c4;
            float4 v = make_float4(0.f, 0.f, 0.f, 0.f);
            if (gk < Ksrc && gn + 3 < H_N)
                v = *(const float4*)(Wsrc + (size_t)gk * H_N + gn);
            ttile[(c4 + 0) * 65 + r] = v.x;
            ttile[(c4 + 1) * 65 + r] = v.y;
            ttile[(c4 + 2) * 65 + r] = v.z;
            ttile[(c4 + 3) * 65 + r] = v.w;
        }
        __syncthreads();
        const int rr = tid >> 2, cc = (tid & 3) * 16;
        short8 s0, s1;
        #pragma unroll
        for (int j = 0; j < 8; ++j) {
            s0[j] = (short)__bfloat16_as_ushort(__float2bfloat16(ttile[rr * 65 + cc + j]));
            s1[j] = (short)__bfloat16_as_ushort(__float2bfloat16(ttile[rr * 65 + cc + 8 + j]));
        }
        *(short8*)(Wdst + (size_t)(n0 + rr) * Kdst + k0 + cc)     = s0;
        *(short8*)(Wdst + (size_t)(n0 + rr) * Kdst + k0 + cc + 8) = s1;
        return;
    }

    // ---------------- bias pad branch (1 block) -----------------------------
    if (tid < 256) {
        b1p[tid]       = (tid < H_N)       ? b1[tid]       : 0.f;
        b1p[tid + 256] = (tid + 256 < H_N) ? b1[tid + 256] : 0.f;
        b2p[tid]       = (tid < H_N)       ? b2[tid]       : 0.f;
        b2p[tid + 256] = (tid + 256 < H_N) ? b2[tid + 256] : 0.f;
    }
}

// ------- kernel 2/3: bf16 MFMA GEMM, 64x64 tile, BK=128, 2-phase, XCD-swz ----
// (verbatim round-4/9 version: passed, absmax 1.0)
template <int KT, bool ROWSUM>
__global__ __launch_bounds__(256) void mfma_gemm(
    const __hip_bfloat16* __restrict__ A,
    const __hip_bfloat16* __restrict__ Bt,
    const float* __restrict__ bias,
    __hip_bfloat16* __restrict__ C,
    float* __restrict__ out)
{
    __shared__ __align__(16) __hip_bfloat16 As[2][64 * 128];
    __shared__ __align__(16) __hip_bfloat16 Bs[2][64 * 128];

    const int tid  = threadIdx.x;
    const int lane = tid & 63;
    const int wid  = tid >> 6;
    const int wm   = wid >> 1;
    const int wn   = wid & 1;

    const int lin  = blockIdx.x;
    const int nb   = (lin & 7) * 64 + (lin >> 3);
    const int row0 = (nb >> 3) * 64;
    const int col0 = (nb & 7) * 64;

    const int lr = lane & 15;
    const int lk = (lane >> 4) * 8;

    f32x4 acc[2][2] = {};

    const int sr = tid >> 4;
    const int sc = (tid & 15) * 8;

    auto STAGE = [&](int buf, int k0) {
        #pragma unroll
        for (int i = 0; i < 4; ++i) {
            __builtin_amdgcn_global_load_lds(
                (g_void*)(A + (size_t)(row0 + sr + i * 16) * KT + k0 + sc),
                (l_void*)(&As[buf][(sr + i * 16) * 128 + sc]), 16, 0, 0);
            __builtin_amdgcn_global_load_lds(
                (g_void*)(Bt + (size_t)(col0 + sr + i * 16) * KT + k0 + sc),
                (l_void*)(&Bs[buf][(sr + i * 16) * 128 + sc]), 16, 0, 0);
        }
    };

    constexpr int NT = KT / 128;
    STAGE(0, 0);
    __syncthreads();

    int cur = 0;
    for (int t = 0; t < NT; ++t) {
        if (t + 1 < NT) STAGE(cur ^ 1, (t + 1) * 128);
        #pragma unroll
        for (int kk = 0; kk < 4; ++kk) {
            short8 a[2], bb[2];
            #pragma unroll
            for (int m = 0; m < 2; ++m)
                a[m] = *(const short8*)(&As[cur][(wm * 32 + m * 16 + lr) * 128 + kk * 32 + lk]);
            #pragma unroll
            for (int n = 0; n < 2; ++n)
                bb[n] = *(const short8*)(&Bs[cur][(wn * 32 + n * 16 + lr) * 128 + kk * 32 + lk]);
            #pragma unroll
            for (int m = 0; m < 2; ++m)
                #pragma unroll
                for (int n = 0; n < 2; ++n)
                    acc[m][n] = __builtin_amdgcn_mfma_f32_16x16x32_bf16(
                        a[m], bb[n], acc[m][n], 0, 0, 0);
        }
        if (t + 1 < NT) {
            __syncthreads();
            cur ^= 1;
        }
    }

    if constexpr (!ROWSUM) {
        __syncthreads();
        float* ctile = (float*)&As[0][0];
        #pragma unroll
        for (int m = 0; m < 2; ++m) {
            const int rbase = wm * 32 + m * 16 + (lane >> 4) * 4;
            #pragma unroll
            for (int n = 0; n < 2; ++n) {
                const int col = wn * 32 + n * 16 + lr;
                const float bv = bias[col0 + col];
                #pragma unroll
                for (int r = 0; r < 4; ++r)
                    ctile[(rbase + r) * 64 + col] = fmaxf(acc[m][n][r] + bv, 0.f);
            }
        }
        __syncthreads();
        const int row = tid >> 2;
        const int cc  = (tid & 3) * 16;
        short8 s0, s1;
        #pragma unroll
        for (int j = 0; j < 8; ++j) {
            s0[j] = (short)__bfloat16_as_ushort(__float2bfloat16(ctile[row * 64 + cc + j]));
            s1[j] = (short)__bfloat16_as_ushort(__float2bfloat16(ctile[row * 64 + cc + 8 + j]));
        }
        *(short8*)(C + (size_t)(row0 + row) * NP + col0 + cc)     = s0;
        *(short8*)(C + (size_t)(row0 + row) * NP + col0 + cc + 8) = s1;
    } else {
        #pragma unroll
        for (int m = 0; m < 2; ++m) {
            float v[4] = {0.f, 0.f, 0.f, 0.f};
            #pragma unroll
            for (int n = 0; n < 2; ++n) {
                const int col = col0 + wn * 32 + n * 16 + lr;
                const float bv = bias[col];
                #pragma unroll
                for (int r = 0; r < 4; ++r)
                    v[r] += fmaxf(acc[m][n][r] + bv, 0.f);
            }
            #pragma unroll
            for (int off = 1; off < 16; off <<= 1)
                #pragma unroll
                for (int r = 0; r < 4; ++r)
                    v[r] += __shfl_xor(v[r], off, 64);
            if (lr == 0) {
                const int row = row0 + wm * 32 + m * 16 + (lane >> 4) * 4;
                #pragma unroll
                for (int r = 0; r < 4; ++r)
                    atomicAdd(out + row + r, v[r]);
            }
        }
    }
}

extern "C" void kernel_launch(void* const* d_in, const int* in_sizes, int n_in,
                              void* d_out, int out_size, void* d_ws, size_t ws_size,
                              hipStream_t stream)
{
    const int*   Xi    = (const int*)  d_in[0];
    const float* Xv    = (const float*)d_in[1];
    const float* fst_t = (const float*)d_in[2];
    const float* sec_t = (const float*)d_in[3];
    const float* W1    = (const float*)d_in[4];
    const float* b1    = (const float*)d_in[5];
    const float* W2    = (const float*)d_in[6];
    const float* b2    = (const float*)d_in[7];
    const float* bias  = (const float*)d_in[8];

    float* out = (float*)d_out;
    char*  wsb = (char*)d_ws;

    __hip_bfloat16* sec_flat = (__hip_bfloat16*)(wsb);                 // 4096*640*2
    __hip_bfloat16* h        = (__hip_bfloat16*)(wsb + 5242880);       // 4096*512*2
    __hip_bfloat16* W1t      = (__hip_bfloat16*)(wsb + 9437184);       // 512*640*2
    __hip_bfloat16* W2t      = (__hip_bfloat16*)(wsb + 10092544);      // 512*512*2
    float*          b1p      = (float*)(wsb + 10616832);               // 512*4
    float*          b2p      = (float*)(wsb + 10618880);               // 512*4

    prep_kernel<<<PREP_GRID, 256, 0, stream>>>(
        Xi, Xv, fst_t, sec_t, bias, W1, b1, W2, b2,
        sec_flat, W1t, W2t, b1p, b2p, out);

    mfma_gemm<K1P, false><<<512, 256, 0, stream>>>(sec_flat, W1t, b1p, h, nullptr);
    mfma_gemm<NP,  true ><<<512, 256, 0, stream>>>(h, W2t, b2p, nullptr, out);
}

// Round 11
// 37.284 us; speedup vs baseline: 2.0833x; 2.0833x over previous
//
#include <hip/hip_runtime.h>
#include <hip/hip_bf16.h>

#define B_SZ 4096
#define F_N  39
#define V_N  100000
#define D_N  16
#define H_N  400
#define K1   624      // F*D
#define K1P  640      // K1 padded to mult of 64
#define NP2  448      // H padded to mult of 64 (7 tiles)

typedef __attribute__((ext_vector_type(8))) short short8;
typedef __attribute__((ext_vector_type(4))) float f32x4;

typedef const __attribute__((address_space(1))) void g_void;
typedef __attribute__((address_space(3))) void l_void;

#define GB       1024                 // gather blocks, 4 rows each
#define W1_TILES (10 * 7)             // K1P/64 x NP2/64
#define W2_TILES (7 * 7)
#define PREP_GRID (GB + W1_TILES + W2_TILES + 1)

// ---- kernel 1: high-MLP gather + fst + FM, fused with weight prep ----------
__global__ __launch_bounds__(256) void prep_kernel(
    const int*   __restrict__ Xi,
    const float* __restrict__ Xv,
    const float* __restrict__ fst_t,
    const float* __restrict__ sec_t,
    const float* __restrict__ bias,
    const float* __restrict__ W1, const float* __restrict__ b1,
    const float* __restrict__ W2, const float* __restrict__ b2,
    __hip_bfloat16* __restrict__ sec_flat,
    __hip_bfloat16* __restrict__ W1t, __hip_bfloat16* __restrict__ W2t,
    float* __restrict__ b1p, float* __restrict__ b2p,
    float* __restrict__ out)
{
    const int bid = blockIdx.x;
    const int tid = threadIdx.x;

    __shared__ float smem[4 * K1];     // 4 rows of sec values (fp32)
    __shared__ int   sidx4[4 * F_N];
    __shared__ float sval4[4 * F_N];
    __shared__ float ttile[64 * 65];   // transpose staging

    if (bid < GB) {
        // ---------------- gather branch: 4 rows, 1 wave per row -------------
        const int r = tid >> 6;        // row 0..3  (= wave id)
        const int l = tid & 63;

        if (tid < 4 * F_N) {           // 156 coalesced idx/val loads
            sidx4[tid] = Xi[bid * (4 * F_N) + tid];
            sval4[tid] = Xv[bid * (4 * F_N) + tid];
        }
        __syncthreads();

        float4 gv[4];
        float  fv[4];
        #pragma unroll
        for (int it = 0; it < 4; ++it) {
            const int t = l + it * 64;             // 0..255
            gv[it] = make_float4(0.f, 0.f, 0.f, 0.f);
            fv[it] = 0.f;
            if (t < 156) {
                const int f = t >> 2, q = t & 3;
                gv[it] = *(const float4*)(sec_t +
                         ((long long)f * V_N + sidx4[r * F_N + f]) * D_N + q * 4);
            }
            if (t >= 156 && t < 156 + F_N) {
                const int ff = t - 156;
                fv[it] = fst_t[(long long)ff * V_N + sidx4[r * F_N + ff]];
            }
        }

        float ssq = 0.f, fstp = 0.f;
        #pragma unroll
        for (int it = 0; it < 4; ++it) {
            const int t = l + it * 64;
            if (t < 160) {
                float4 v = make_float4(0.f, 0.f, 0.f, 0.f);
                if (t < 156) {
                    const float val = sval4[r * F_N + (t >> 2)];
                    v.x = gv[it].x * val; v.y = gv[it].y * val;
                    v.z = gv[it].z * val; v.w = gv[it].w * val;
                    *(float4*)(smem + r * K1 + t * 4) = v;
                    ssq += v.x * v.x + v.y * v.y + v.z * v.z + v.w * v.w;
                }
                ushort4 pk;
                pk.x = __bfloat16_as_ushort(__float2bfloat16(v.x));
                pk.y = __bfloat16_as_ushort(__float2bfloat16(v.y));
                pk.z = __bfloat16_as_ushort(__float2bfloat16(v.z));
                pk.w = __bfloat16_as_ushort(__float2bfloat16(v.w));
                *(ushort4*)(sec_flat + (size_t)(bid * 4 + r) * K1P + t * 4) = pk;
            }
            if (t >= 156 && t < 156 + F_N)
                fstp += fv[it] * sval4[r * F_N + (t - 156)];
        }

        float part = fstp - 0.5f * ssq;
        if (l < D_N) {
            float sd = 0.f;
            #pragma unroll
            for (int f = 0; f < F_N; ++f)
                sd += smem[r * K1 + f * D_N + l];
            part += 0.5f * sd * sd;
        }
        #pragma unroll
        for (int off = 1; off < 64; off <<= 1)
            part += __shfl_xor(part, off, 64);
        if (l == 0) out[bid * 4 + r] = part + bias[0];
        return;
    }

    int tb = bid - GB;
    if (tb < W1_TILES + W2_TILES) {
        // ---------------- weight transpose branch ---------------------------
        // src W [Ksrc][H_N] fp32 -> dst Wt [NP2][Kdst] bf16 (zero-padded)
        const float* Wsrc; __hip_bfloat16* Wdst;
        int Ksrc, Kdst, kb, nb2;
        if (tb < W1_TILES) { Wsrc = W1; Wdst = W1t; Ksrc = K1;  Kdst = K1P; kb = tb / 7; nb2 = tb % 7; }
        else { tb -= W1_TILES; Wsrc = W2; Wdst = W2t; Ksrc = H_N; Kdst = NP2; kb = tb / 7; nb2 = tb % 7; }
        const int k0 = kb * 64, n0 = nb2 * 64;
        #pragma unroll
        for (int p = 0; p < 4; ++p) {
            const int r  = (tid >> 4) + p * 16;   // src row (k)
            const int c4 = (tid & 15) * 4;        // src col (n)
            const int gk = k0 + r, gn = n0 + c4;
            float4 v = make_float4(0.f, 0.f, 0.f, 0.f);
            if (gk < Ksrc && gn + 3 < H_N)
                v = *(const float4*)(Wsrc + (size_t)gk * H_N + gn);
            ttile[(c4 + 0) * 65 + r] = v.x;
            ttile[(c4 + 1) * 65 + r] = v.y;
            ttile[(c4 + 2) * 65 + r] = v.z;
            ttile[(c4 + 3) * 65 + r] = v.w;
        }
        __syncthreads();
        const int rr = tid >> 2, cc = (tid & 3) * 16;
        short8 s0, s1;
        #pragma unroll
        for (int j = 0; j < 8; ++j) {
            s0[j] = (short)__bfloat16_as_ushort(__float2bfloat16(ttile[rr * 65 + cc + j]));
            s1[j] = (short)__bfloat16_as_ushort(__float2bfloat16(ttile[rr * 65 + cc + 8 + j]));
        }
        *(short8*)(Wdst + (size_t)(n0 + rr) * Kdst + k0 + cc)     = s0;
        *(short8*)(Wdst + (size_t)(n0 + rr) * Kdst + k0 + cc + 8) = s1;
        return;
    }

    // ---------------- bias pad branch (1 block) -----------------------------
    if (tid < 256) {
        b1p[tid] = (tid < H_N) ? b1[tid] : 0.f;
        b2p[tid] = (tid < H_N) ? b2[tid] : 0.f;
        if (tid + 256 < NP2) {
            b1p[tid + 256] = (tid + 256 < H_N) ? b1[tid + 256] : 0.f;
            b2p[tid + 256] = (tid + 256 < H_N) ? b2[tid + 256] : 0.f;
        }
    }
}

// ------- kernel 2/3: bf16 MFMA GEMM, 128x64 tile, BK=64, 2-phase, XCD-swz ---
// C = relu(A @ Bt^T + bias)   (A: [M][KT] bf16, Bt: [NP2][KT] bf16 = W^T)
// ROWSUM: atomicAdd per-row sums of relu(...) into out instead of storing C
// grid = 224 blocks (32 row-panels x 7 col-tiles), 224 % 8 == 0 -> bijective
template <int KT, bool ROWSUM>
__global__ __launch_bounds__(256) void mfma_gemm(
    const __hip_bfloat16* __restrict__ A,
    const __hip_bfloat16* __restrict__ Bt,
    const float* __restrict__ bias,
    __hip_bfloat16* __restrict__ C,
    float* __restrict__ out)
{
    __shared__ __align__(16) __hip_bfloat16 As[2][128 * 64];   // 32 KB
    __shared__ __align__(16) __hip_bfloat16 Bs[2][64 * 64];    // 16 KB

    const int tid  = threadIdx.x;
    const int lane = tid & 63;
    const int w    = tid >> 6;       // wave 0..3, rows w*32..w*32+31
    const int lr   = lane & 15;
    const int lg4  = lane >> 4;
    const int lk   = lg4 * 8;

    // XCD-chunked swizzle: 28 consecutive tiles per XCD (4 row-panels)
    const int lin  = blockIdx.x;
    const int swz  = (lin & 7) * 28 + (lin >> 3);
    const int row0 = (swz / 7) * 128;
    const int col0 = (swz % 7) * 64;

    const int sr = tid >> 3;         // staging row 0..31
    const int sc = (tid & 7) * 8;    // 16B chunk

    f32x4 acc[2][4] = {};

    auto STAGE = [&](int buf, int k0) {
        #pragma unroll
        for (int i = 0; i < 4; ++i)
            __builtin_amdgcn_global_load_lds(
                (g_void*)(A + (size_t)(row0 + sr + i * 32) * KT + k0 + sc),
                (l_void*)(&As[buf][(sr + i * 32) * 64 + sc]), 16, 0, 0);
        #pragma unroll
        for (int i = 0; i < 2; ++i)
            __builtin_amdgcn_global_load_lds(
                (g_void*)(Bt + (size_t)(col0 + sr + i * 32) * KT + k0 + sc),
                (l_void*)(&Bs[buf][(sr + i * 32) * 64 + sc]), 16, 0, 0);
    };

    constexpr int NT = KT / 64;
    STAGE(0, 0);
    __syncthreads();

    int cur = 0;
    for (int t = 0; t < NT; ++t) {
        if (t + 1 < NT) STAGE(cur ^ 1, (t + 1) * 64);   // issue next FIRST
        #pragma unroll
        for (int ks = 0; ks < 2; ++ks) {
            short8 a[2], bb[4];
            #pragma unroll
            for (int m = 0; m < 2; ++m)
                a[m] = *(const short8*)(&As[cur][(w * 32 + m * 16 + lr) * 64 + ks * 32 + lk]);
            #pragma unroll
            for (int n = 0; n < 4; ++n)
                bb[n] = *(const short8*)(&Bs[cur][(n * 16 + lr) * 64 + ks * 32 + lk]);
            #pragma unroll
            for (int m = 0; m < 2; ++m)
                #pragma unroll
                for (int n = 0; n < 4; ++n)
                    acc[m][n] = __builtin_amdgcn_mfma_f32_16x16x32_bf16(
                        a[m], bb[n], acc[m][n], 0, 0, 0);
        }
        if (t + 1 < NT) {
            __syncthreads();
            cur ^= 1;
        }
    }

    // epilogue — C/D layout: col = lane&15, row = (lane>>4)*4 + reg  [m89]
    if constexpr (!ROWSUM) {
        __syncthreads();                       // done reading As/Bs
        float* ctile = (float*)&As[0][0];      // 128x64 f32 = 32 KB (= As dbuf)
        #pragma unroll
        for (int m = 0; m < 2; ++m) {
            const int rb = w * 32 + m * 16 + lg4 * 4;
            #pragma unroll
            for (int n = 0; n < 4; ++n) {
                const int col = n * 16 + lr;
                const float bv = bias[col0 + col];
                #pragma unroll
                for (int r = 0; r < 4; ++r)
                    ctile[(rb + r) * 64 + col] = fmaxf(acc[m][n][r] + bv, 0.f);
            }
        }
        __syncthreads();
        #pragma unroll
        for (int p = 0; p < 2; ++p) {
            const int row = (tid >> 2) + p * 64;
            const int cc  = (tid & 3) * 16;
            short8 s0, s1;
            #pragma unroll
            for (int j = 0; j < 8; ++j) {
                s0[j] = (short)__bfloat16_as_ushort(__float2bfloat16(ctile[row * 64 + cc + j]));
                s1[j] = (short)__bfloat16_as_ushort(__float2bfloat16(ctile[row * 64 + cc + 8 + j]));
            }
            *(short8*)(C + (size_t)(row0 + row) * NP2 + col0 + cc)     = s0;
            *(short8*)(C + (size_t)(row0 + row) * NP2 + col0 + cc + 8) = s1;
        }
    } else {
        #pragma unroll
        for (int m = 0; m < 2; ++m) {
            float v[4] = {0.f, 0.f, 0.f, 0.f};
            #pragma unroll
            for (int n = 0; n < 4; ++n) {
                const int col = col0 + n * 16 + lr;
                const float bv = bias[col];
                #pragma unroll
                for (int r = 0; r < 4; ++r)
                    v[r] += fmaxf(acc[m][n][r] + bv, 0.f);
            }
            #pragma unroll
            for (int off = 1; off < 16; off <<= 1)
                #pragma unroll
                for (int r = 0; r < 4; ++r)
                    v[r] += __shfl_xor(v[r], off, 64);
            if (lr == 0) {
                const int row = row0 + w * 32 + m * 16 + lg4 * 4;
                #pragma unroll
                for (int r = 0; r < 4; ++r)
                    atomicAdd(out + row + r, v[r]);
            }
        }
    }
}

extern "C" void kernel_launch(void* const* d_in, const int* in_sizes, int n_in,
                              void* d_out, int out_size, void* d_ws, size_t ws_size,
                              hipStream_t stream)
{
    const int*   Xi    = (const int*)  d_in[0];
    const float* Xv    = (const float*)d_in[1];
    const float* fst_t = (const float*)d_in[2];
    const float* sec_t = (const float*)d_in[3];
    const float* W1    = (const float*)d_in[4];
    const float* b1    = (const float*)d_in[5];
    const float* W2    = (const float*)d_in[6];
    const float* b2    = (const float*)d_in[7];
    const float* bias  = (const float*)d_in[8];

    float* out = (float*)d_out;
    char*  wsb = (char*)d_ws;

    __hip_bfloat16* sec_flat = (__hip_bfloat16*)(wsb);                // 4096*640*2 = 5242880
    __hip_bfloat16* h        = (__hip_bfloat16*)(wsb + 5242880);      // 4096*448*2 = 3670016
    __hip_bfloat16* W1t      = (__hip_bfloat16*)(wsb + 8912896);      // 448*640*2  = 573440
    __hip_bfloat16* W2t      = (__hip_bfloat16*)(wsb + 9486336);      // 448*448*2  = 401408
    float*          b1p      = (float*)(wsb + 9887744);               // 448*4
    float*          b2p      = (float*)(wsb + 9889536);               // 448*4

    prep_kernel<<<PREP_GRID, 256, 0, stream>>>(
        Xi, Xv, fst_t, sec_t, bias, W1, b1, W2, b2,
        sec_flat, W1t, W2t, b1p, b2p, out);

    mfma_gemm<K1P, false><<<224, 256, 0, stream>>>(sec_flat, W1t, b1p, h, nullptr);
    mfma_gemm<NP2, true ><<<224, 256, 0, stream>>>(h, W2t, b2p, nullptr, out);
}

// Round 12
// 31.083 us; speedup vs baseline: 2.4989x; 1.1995x over previous
//
#include <hip/hip_runtime.h>
#include <hip/hip_bf16.h>

#define B_SZ 4096
#define F_N  39
#define V_N  100000
#define D_N  16
#define H_N  400
#define K1   624      // F*D
#define K1P  640      // K1 padded to mult of 64
#define NP2  448      // H padded to mult of 64 (7 tiles)

typedef __attribute__((ext_vector_type(8))) short short8;
typedef __attribute__((ext_vector_type(4))) float f32x4;

typedef const __attribute__((address_space(1))) void g_void;
typedef __attribute__((address_space(3))) void l_void;

#define GB       1024                 // gather blocks, 4 rows each
#define W1_TILES (10 * 7)             // K1P/64 x NP2/64
#define W2_TILES (7 * 7)
#define PREP_GRID (GB + W1_TILES + W2_TILES + 1)

// Chunk-XOR swizzle (both-sides, rule #21): 16B chunk c of row r stored at
// global chunk (c&~7)|((c^r)&7); global_load_lds stages linearly; ds_read
// XORs back. Breaks the 16-way LDS bank conflict of 128B-stride rows.

// ---- kernel 1: high-MLP gather + fst + FM, fused with weight prep ----------
__global__ __launch_bounds__(256) void prep_kernel(
    const int*   __restrict__ Xi,
    const float* __restrict__ Xv,
    const float* __restrict__ fst_t,
    const float* __restrict__ sec_t,
    const float* __restrict__ bias,
    const float* __restrict__ W1, const float* __restrict__ b1,
    const float* __restrict__ W2, const float* __restrict__ b2,
    __hip_bfloat16* __restrict__ sec_flat,
    __hip_bfloat16* __restrict__ W1t, __hip_bfloat16* __restrict__ W2t,
    float* __restrict__ b1p, float* __restrict__ b2p,
    float* __restrict__ out)
{
    const int bid = blockIdx.x;
    const int tid = threadIdx.x;

    __shared__ float smem[4 * K1];     // 4 rows of sec values (fp32)
    __shared__ int   sidx4[4 * F_N];
    __shared__ float sval4[4 * F_N];
    __shared__ float ttile[64 * 65];   // transpose staging

    if (bid < GB) {
        // ---------------- gather branch: 4 rows, 1 wave per row -------------
        const int r = tid >> 6;        // row 0..3  (= wave id)
        const int l = tid & 63;

        if (tid < 4 * F_N) {           // 156 coalesced idx/val loads
            sidx4[tid] = Xi[bid * (4 * F_N) + tid];
            sval4[tid] = Xv[bid * (4 * F_N) + tid];
        }
        __syncthreads();

        float4 gv[4];
        float  fv[4];
        #pragma unroll
        for (int it = 0; it < 4; ++it) {
            const int t = l + it * 64;             // 0..255
            gv[it] = make_float4(0.f, 0.f, 0.f, 0.f);
            fv[it] = 0.f;
            if (t < 156) {
                const int f = t >> 2, q = t & 3;
                gv[it] = *(const float4*)(sec_t +
                         ((long long)f * V_N + sidx4[r * F_N + f]) * D_N + q * 4);
            }
            if (t >= 156 && t < 156 + F_N) {
                const int ff = t - 156;
                fv[it] = fst_t[(long long)ff * V_N + sidx4[r * F_N + ff]];
            }
        }

        const int grow = bid * 4 + r;
        float ssq = 0.f, fstp = 0.f;
        #pragma unroll
        for (int it = 0; it < 4; ++it) {
            const int t = l + it * 64;
            if (t < 160) {
                float4 v = make_float4(0.f, 0.f, 0.f, 0.f);
                if (t < 156) {
                    const float val = sval4[r * F_N + (t >> 2)];
                    v.x = gv[it].x * val; v.y = gv[it].y * val;
                    v.z = gv[it].z * val; v.w = gv[it].w * val;
                    *(float4*)(smem + r * K1 + t * 4) = v;
                    ssq += v.x * v.x + v.y * v.y + v.z * v.z + v.w * v.w;
                }
                ushort4 pk;
                pk.x = __bfloat16_as_ushort(__float2bfloat16(v.x));
                pk.y = __bfloat16_as_ushort(__float2bfloat16(v.y));
                pk.z = __bfloat16_as_ushort(__float2bfloat16(v.z));
                pk.w = __bfloat16_as_ushort(__float2bfloat16(v.w));
                // pre-swizzled store: chunk (t>>1), half (t&1)
                const int ch = t >> 1;
                const int cs = (ch & ~7) | ((ch ^ grow) & 7);
                *(ushort4*)(sec_flat + (size_t)grow * K1P + cs * 8 + (t & 1) * 4) = pk;
            }
            if (t >= 156 && t < 156 + F_N)
                fstp += fv[it] * sval4[r * F_N + (t - 156)];
        }

        float part = fstp - 0.5f * ssq;
        if (l < D_N) {
            float sd = 0.f;
            #pragma unroll
            for (int f = 0; f < F_N; ++f)
                sd += smem[r * K1 + f * D_N + l];
            part += 0.5f * sd * sd;
        }
        #pragma unroll
        for (int off = 1; off < 64; off <<= 1)
            part += __shfl_xor(part, off, 64);
        if (l == 0) out[grow] = part + bias[0];
        return;
    }

    int tb = bid - GB;
    if (tb < W1_TILES + W2_TILES) {
        // ---------------- weight transpose branch (pre-swizzled dst) --------
        const float* Wsrc; __hip_bfloat16* Wdst;
        int Ksrc, Kdst, kb, nb2;
        if (tb < W1_TILES) { Wsrc = W1; Wdst = W1t; Ksrc = K1;  Kdst = K1P; kb = tb / 7; nb2 = tb % 7; }
        else { tb -= W1_TILES; Wsrc = W2; Wdst = W2t; Ksrc = H_N; Kdst = NP2; kb = tb / 7; nb2 = tb % 7; }
        const int k0 = kb * 64, n0 = nb2 * 64;
        #pragma unroll
        for (int p = 0; p < 4; ++p) {
            const int r  = (tid >> 4) + p * 16;   // src row (k)
            const int c4 = (tid & 15) * 4;        // src col (n)
            const int gk = k0 + r, gn = n0 + c4;
            float4 v = make_float4(0.f, 0.f, 0.f, 0.f);
            if (gk < Ksrc && gn + 3 < H_N)
                v = *(const float4*)(Wsrc + (size_t)gk * H_N + gn);
            ttile[(c4 + 0) * 65 + r] = v.x;
            ttile[(c4 + 1) * 65 + r] = v.y;
            ttile[(c4 + 2) * 65 + r] = v.z;
            ttile[(c4 + 3) * 65 + r] = v.w;
        }
        __syncthreads();
        const int rr = tid >> 2, cc = (tid & 3) * 16;
        const int n  = n0 + rr;
        short8 s0, s1;
        #pragma unroll
        for (int j = 0; j < 8; ++j) {
            s0[j] = (short)__bfloat16_as_ushort(__float2bfloat16(ttile[rr * 65 + cc + j]));
            s1[j] = (short)__bfloat16_as_ushort(__float2bfloat16(ttile[rr * 65 + cc + 8 + j]));
        }
        const int c0  = (k0 + cc) >> 3;
        const int c1  = c0 + 1;
        const int c0s = (c0 & ~7) | ((c0 ^ n) & 7);
        const int c1s = (c1 & ~7) | ((c1 ^ n) & 7);
        *(short8*)(Wdst + (size_t)n * Kdst + c0s * 8) = s0;
        *(short8*)(Wdst + (size_t)n * Kdst + c1s * 8) = s1;
        return;
    }

    // ---------------- bias pad branch (1 block) -----------------------------
    if (tid < 256) {
        b1p[tid] = (tid < H_N) ? b1[tid] : 0.f;
        b2p[tid] = (tid < H_N) ? b2[tid] : 0.f;
        if (tid + 256 < NP2) {
            b1p[tid + 256] = (tid + 256 < H_N) ? b1[tid + 256] : 0.f;
            b2p[tid + 256] = (tid + 256 < H_N) ? b2[tid + 256] : 0.f;
        }
    }
}

// ---- kernel 2/3: bf16 MFMA GEMM, 64x64 tile, 3-buf counted-vmcnt pipeline --
// C = relu(A @ Bt^T + bias); ROWSUM: atomicAdd row sums into out.
// grid = 448 (64 row-panels x 7 col-tiles); 448 % 8 == 0 -> bijective swizzle
template <int KT, bool ROWSUM>
__global__ __launch_bounds__(256) void mfma_gemm(
    const __hip_bfloat16* __restrict__ A,
    const __hip_bfloat16* __restrict__ Bt,
    const float* __restrict__ bias,
    __hip_bfloat16* __restrict__ C,
    float* __restrict__ out)
{
    __shared__ __align__(16) __hip_bfloat16 As[3][64 * 64];  // 24 KB
    __shared__ __align__(16) __hip_bfloat16 Bs[3][64 * 64];  // 24 KB

    const int tid  = threadIdx.x;
    const int lane = tid & 63;
    const int wid  = tid >> 6;       // 4 waves: 2 (M) x 2 (N)
    const int wm   = wid >> 1;
    const int wn   = wid & 1;
    const int lr   = lane & 15;
    const int lg4  = lane >> 4;

    // XCD-chunked swizzle: 56 consecutive tiles per XCD (8 row-panels)
    const int lin  = blockIdx.x;
    const int swz  = (lin & 7) * 56 + (lin >> 3);
    const int row0 = (swz / 7) * 64;
    const int col0 = (swz % 7) * 64;

    const int sr = tid >> 3;         // staging row 0..31
    const int sc = (tid & 7) * 8;    // 16B chunk

    // preload bias, pinned before the pipeline so vmcnt ledger stays pure
    float bvv[2];
    #pragma unroll
    for (int n = 0; n < 2; ++n)
        bvv[n] = bias[col0 + wn * 32 + n * 16 + lr];
    asm volatile("" :: "v"(bvv[0]), "v"(bvv[1]));
    asm volatile("s_waitcnt vmcnt(0)" ::: "memory");

    auto STAGE = [&](int buf, int k0) {   // 4 gload_lds per thread
        #pragma unroll
        for (int i = 0; i < 2; ++i) {
            __builtin_amdgcn_global_load_lds(
                (g_void*)(A + (size_t)(row0 + i * 32 + sr) * KT + k0 + sc),
                (l_void*)(&As[buf][(i * 32 + sr) * 64 + sc]), 16, 0, 0);
            __builtin_amdgcn_global_load_lds(
                (g_void*)(Bt + (size_t)(col0 + i * 32 + sr) * KT + k0 + sc),
                (l_void*)(&Bs[buf][(i * 32 + sr) * 64 + sc]), 16, 0, 0);
        }
    };

    constexpr int NT = KT / 64;
    STAGE(0, 0);
    STAGE(1, 64);

    f32x4 acc[2][2] = {};
    for (int t = 0; t < NT; ++t) {
        // wait for oldest stage only (4 instr/stage); never drain mid-loop
        if (t + 1 < NT) asm volatile("s_waitcnt vmcnt(4)" ::: "memory");
        else            asm volatile("s_waitcnt vmcnt(0)" ::: "memory");
        __builtin_amdgcn_s_barrier();
        if (t + 2 < NT) STAGE((t + 2) % 3, (t + 2) * 64);

        const int cb = t % 3;
        #pragma unroll
        for (int ks = 0; ks < 2; ++ks) {
            short8 a[2], bb[2];
            #pragma unroll
            for (int m = 0; m < 2; ++m) {
                const int row = wm * 32 + m * 16 + lr;
                const int ch  = (ks * 4 + lg4) ^ (row & 7);
                a[m] = *(const short8*)(&As[cb][row * 64 + ch * 8]);
            }
            #pragma unroll
            for (int n = 0; n < 2; ++n) {
                const int row = wn * 32 + n * 16 + lr;
                const int ch  = (ks * 4 + lg4) ^ (row & 7);
                bb[n] = *(const short8*)(&Bs[cb][row * 64 + ch * 8]);
            }
            #pragma unroll
            for (int m = 0; m < 2; ++m)
                #pragma unroll
                for (int n = 0; n < 2; ++n)
                    acc[m][n] = __builtin_amdgcn_mfma_f32_16x16x32_bf16(
                        a[m], bb[n], acc[m][n], 0, 0, 0);
        }
    }

    // epilogue — C/D layout: col = lane&15, row = (lane>>4)*4 + reg  [m89]
    if constexpr (!ROWSUM) {
        __syncthreads();                       // staging done, reads done
        float* ctile = (float*)&As[0][0];      // 64x64 f32 = 16 KB
        #pragma unroll
        for (int m = 0; m < 2; ++m) {
            const int rb = wm * 32 + m * 16 + lg4 * 4;
            #pragma unroll
            for (int n = 0; n < 2; ++n) {
                const int col = wn * 32 + n * 16 + lr;
                #pragma unroll
                for (int r = 0; r < 4; ++r)
                    ctile[(rb + r) * 64 + col] = fmaxf(acc[m][n][r] + bvv[n], 0.f);
            }
        }
        __syncthreads();
        const int row = tid >> 2;              // 0..63
        const int cc  = (tid & 3) * 16;
        short8 s0, s1;
        #pragma unroll
        for (int j = 0; j < 8; ++j) {
            s0[j] = (short)__bfloat16_as_ushort(__float2bfloat16(ctile[row * 64 + cc + j]));
            s1[j] = (short)__bfloat16_as_ushort(__float2bfloat16(ctile[row * 64 + cc + 8 + j]));
        }
        // pre-swizzled h store (rows of h are GEMM2's A rows)
        const int c0  = (col0 + cc) >> 3;
        const int c1  = c0 + 1;
        const int c0s = (c0 & ~7) | ((c0 ^ row) & 7);
        const int c1s = (c1 & ~7) | ((c1 ^ row) & 7);
        *(short8*)(C + (size_t)(row0 + row) * NP2 + c0s * 8) = s0;
        *(short8*)(C + (size_t)(row0 + row) * NP2 + c1s * 8) = s1;
    } else {
        #pragma unroll
        for (int m = 0; m < 2; ++m) {
            float v[4] = {0.f, 0.f, 0.f, 0.f};
            #pragma unroll
            for (int n = 0; n < 2; ++n) {
                #pragma unroll
                for (int r = 0; r < 4; ++r)
                    v[r] += fmaxf(acc[m][n][r] + bvv[n], 0.f);
            }
            #pragma unroll
            for (int off = 1; off < 16; off <<= 1)
                #pragma unroll
                for (int r = 0; r < 4; ++r)
                    v[r] += __shfl_xor(v[r], off, 64);
            if (lr == 0) {
                const int row = row0 + wm * 32 + m * 16 + lg4 * 4;
                #pragma unroll
                for (int r = 0; r < 4; ++r)
                    atomicAdd(out + row + r, v[r]);
            }
        }
    }
}

extern "C" void kernel_launch(void* const* d_in, const int* in_sizes, int n_in,
                              void* d_out, int out_size, void* d_ws, size_t ws_size,
                              hipStream_t stream)
{
    const int*   Xi    = (const int*)  d_in[0];
    const float* Xv    = (const float*)d_in[1];
    const float* fst_t = (const float*)d_in[2];
    const float* sec_t = (const float*)d_in[3];
    const float* W1    = (const float*)d_in[4];
    const float* b1    = (const float*)d_in[5];
    const float* W2    = (const float*)d_in[6];
    const float* b2    = (const float*)d_in[7];
    const float* bias  = (const float*)d_in[8];

    float* out = (float*)d_out;
    char*  wsb = (char*)d_ws;

    __hip_bfloat16* sec_flat = (__hip_bfloat16*)(wsb);                // 4096*640*2 = 5242880
    __hip_bfloat16* h        = (__hip_bfloat16*)(wsb + 5242880);      // 4096*448*2 = 3670016
    __hip_bfloat16* W1t      = (__hip_bfloat16*)(wsb + 8912896);      // 448*640*2  = 573440
    __hip_bfloat16* W2t      = (__hip_bfloat16*)(wsb + 9486336);      // 448*448*2  = 401408
    float*          b1p      = (float*)(wsb + 9887744);               // 448*4
    float*          b2p      = (float*)(wsb + 9889536);               // 448*4

    prep_kernel<<<PREP_GRID, 256, 0, stream>>>(
        Xi, Xv, fst_t, sec_t, bias, W1, b1, W2, b2,
        sec_flat, W1t, W2t, b1p, b2p, out);

    mfma_gemm<K1P, false><<<448, 256, 0, stream>>>(sec_flat, W1t, b1p, h, nullptr);
    mfma_gemm<NP2, true ><<<448, 256, 0, stream>>>(h, W2t, b2p, nullptr, out);
}